// Round 4
// baseline (617.553 us; speedup 1.0000x reference)
//
#include <hip/hip_runtime.h>
#include <stdint.h>

// Problem constants
#define T_    256
#define B_    4
#define U_    64
#define EENC  1024
#define EDEC  640
#define J_    640
#define V_    4096

typedef unsigned short u16;
typedef unsigned int   u32;
typedef __bf16 bf16x8 __attribute__((ext_vector_type(8)));
typedef short  s16x8  __attribute__((ext_vector_type(8)));
typedef float  f32x4  __attribute__((ext_vector_type(4)));

__device__ __forceinline__ u16 f2bf(float f) {
    u32 u = __builtin_bit_cast(u32, f);
    u = (u + 0x7FFFu + ((u >> 16) & 1u)) >> 16;
    return (u16)u;
}
__device__ __forceinline__ float bf2f(u16 b) {
    return __builtin_bit_cast(float, (u32)b << 16);
}

// packed joint: two bf16 lanes of enc + dec -> relu(e+d) packed bf16x2 (RNE)
__device__ __forceinline__ u32 joint2(u32 e, u32 d) {
    float elo = __builtin_bit_cast(float, e << 16);
    float ehi = __builtin_bit_cast(float, e & 0xFFFF0000u);
    float dlo = __builtin_bit_cast(float, d << 16);
    float dhi = __builtin_bit_cast(float, d & 0xFFFF0000u);
    float slo = fmaxf(elo + dlo, 0.f);
    float shi = fmaxf(ehi + dhi, 0.f);
    u32 r;
    asm("v_cvt_pk_bf16_f32 %0, %1, %2" : "=v"(r) : "v"(slo), "v"(shi));
    return r;
}
__device__ __forceinline__ uint4 joint4(uint4 e, uint4 d) {
    uint4 j;
    j.x = joint2(e.x, d.x); j.y = joint2(e.y, d.y);
    j.z = joint2(e.z, d.z); j.w = joint2(e.w, d.w);
    return j;
}

// ---------------- f32 -> bf16 convert (vectorized x4) ----------------
__global__ __launch_bounds__(256) void cvt_bf16(const float* __restrict__ src,
                                                u16* __restrict__ dst, int n4) {
    int i = blockIdx.x * 256 + threadIdx.x;
    if (i < n4) {
        float4 v = reinterpret_cast<const float4*>(src)[i];
        ushort4 o;
        o.x = f2bf(v.x); o.y = f2bf(v.y); o.z = f2bf(v.z); o.w = f2bf(v.w);
        reinterpret_cast<ushort4*>(dst)[i] = o;
    }
}

// ---------------- LayerNorm over J=640 + bias + affine, bf16 out, transposed ----------------
__global__ __launch_bounds__(256) void ln_kernel(const float* __restrict__ proj,
                                                 const float* __restrict__ bias,
                                                 const float* __restrict__ gamma,
                                                 const float* __restrict__ beta,
                                                 u16* __restrict__ out,
                                                 int BDIM, int OUTER) {
    int pr = blockIdx.x;
    int b = pr % BDIM, outer = pr / BDIM;
    const float* row = proj + (size_t)pr * J_;
    int tid = threadIdx.x;

    float x0 = row[tid] + bias[tid];
    float x1 = row[tid + 256] + bias[tid + 256];
    float x2 = 0.f;
    bool has3 = (tid < J_ - 512);
    if (has3) x2 = row[tid + 512] + bias[tid + 512];

    float s1 = x0 + x1 + x2;
    float s2 = x0 * x0 + x1 * x1 + x2 * x2;
    for (int off = 32; off; off >>= 1) {
        s1 += __shfl_down(s1, off, 64);
        s2 += __shfl_down(s2, off, 64);
    }
    __shared__ float ws1[4], ws2[4];
    int w = tid >> 6, lane = tid & 63;
    if (lane == 0) { ws1[w] = s1; ws2[w] = s2; }
    __syncthreads();
    float S1 = ws1[0] + ws1[1] + ws1[2] + ws1[3];
    float S2 = ws2[0] + ws2[1] + ws2[2] + ws2[3];
    float mu = S1 * (1.f / J_);
    float var = S2 * (1.f / J_) - mu * mu;
    float inv = 1.0f / sqrtf(var + 1e-5f);

    size_t orow = ((size_t)b * OUTER + outer) * J_;
    out[orow + tid]       = f2bf((x0 - mu) * inv * gamma[tid]       + beta[tid]);
    out[orow + tid + 256] = f2bf((x1 - mu) * inv * gamma[tid + 256] + beta[tid + 256]);
    if (has3)
        out[orow + tid + 512] = f2bf((x2 - mu) * inv * gamma[tid + 512] + beta[tid + 512]);
}

// ---------------- m97-structure 128x128 GEMM (stage-1 projections) ----------------
__global__ __launch_bounds__(256) void gemm_bt(const u16* __restrict__ A,
                                               const u16* __restrict__ Bt,
                                               float* __restrict__ C,
                                               const float* __restrict__ bias,
                                               int K, int ldc) {
    __shared__ u16 As[128 * 64];
    __shared__ u16 Bs[128 * 64];
    const int tid = threadIdx.x;
    const int w = tid >> 6, lane = tid & 63;
    const int wr = w >> 1, wc = w & 1;
    const size_t m0 = (size_t)blockIdx.y * 128;
    const size_t n0 = (size_t)blockIdx.x * 128;

    f32x4 acc[4][4] = {};

    const int l3 = lane >> 3;
    const int c8 = (lane & 7) * 8;
    const int nkt = K >> 6;

    for (int kt = 0; kt < nkt; ++kt) {
        if (kt) __syncthreads();
        const int k0 = kt << 6;
#pragma unroll
        for (int i = 0; i < 4; ++i) {
            const int c = w * 4 + i;
            const int r = c * 8 + l3;
            const u16* ga = A  + (m0 + r) * (size_t)K + k0 + c8;
            const u16* gb = Bt + (n0 + r) * (size_t)K + k0 + c8;
            __builtin_amdgcn_global_load_lds(
                (const __attribute__((address_space(1))) void*)ga,
                (__attribute__((address_space(3))) void*)(As + c * 512), 16, 0, 0);
            __builtin_amdgcn_global_load_lds(
                (const __attribute__((address_space(1))) void*)gb,
                (__attribute__((address_space(3))) void*)(Bs + c * 512), 16, 0, 0);
        }
        __syncthreads();

#pragma unroll
        for (int kk = 0; kk < 2; ++kk) {
            bf16x8 af[4], bfr[4];
#pragma unroll
            for (int i = 0; i < 4; ++i) {
                int ra = wr * 64 + i * 16 + (lane & 15);
                af[i] = *reinterpret_cast<const bf16x8*>(As + ra * 64 + kk * 32 + (lane >> 4) * 8);
                int rb = wc * 64 + i * 16 + (lane & 15);
                bfr[i] = *reinterpret_cast<const bf16x8*>(Bs + rb * 64 + kk * 32 + (lane >> 4) * 8);
            }
#pragma unroll
            for (int i = 0; i < 4; ++i)
#pragma unroll
                for (int j = 0; j < 4; ++j)
                    acc[i][j] = __builtin_amdgcn_mfma_f32_16x16x32_bf16(af[i], bfr[j], acc[i][j], 0, 0, 0);
        }
    }

    const int r4 = (lane >> 4) * 4;
    const int cl = lane & 15;
#pragma unroll
    for (int i = 0; i < 4; ++i) {
#pragma unroll
        for (int j = 0; j < 4; ++j) {
            size_t grow = m0 + wr * 64 + i * 16 + r4;
            size_t gcol = n0 + wc * 64 + j * 16 + cl;
            float bv = bias ? bias[gcol] : 0.f;
#pragma unroll
            for (int r = 0; r < 4; ++r)
                C[(grow + r) * (size_t)ldc + gcol] = acc[i][j][r] + bv;
        }
    }
}

// ---------------- fused joint + vocab projection ----------------
// C[m][v] = relu(enc[b,t,:] + dec[b,u,:]) . Wout[v,:] + b_out,  m=(b,t,u)
// 256x256 tile, BK=64, 512 thr (8 waves 2Mx4N), per-wave 128x64, acc[8][4].
// A is COMPUTED during staging: per-thread enc/dec bf16 loads -> f32 add ->
// relu -> cvt_pk_bf16 -> ds_write_b128 into the XOR-swizzled LDS layout.
// B via gload_lds (pre-swizzled source). 4 phases/K-tile; one vmcnt(0)/tile
// (2-3 phases of cover); setprio around MFMA; nt C-stores; XCD n-ownership.
#define BK   64
#define BIGK 640
#define BIGN 4096
#define NT_  (BIGK / BK)

__global__ __launch_bounds__(512, 2) void gemm_big(const u16* __restrict__ encln,
                                                   const u16* __restrict__ decln,
                                                   const u16* __restrict__ Bt,
                                                   float* __restrict__ C,
                                                   const float* __restrict__ bias) {
    __shared__ u16 lds[2][2][256 * BK];   // [buf][0=A,1=B]; 128 KiB

    const int tid = threadIdx.x;
    const int w = tid >> 6, lane = tid & 63;
    const int wr = w >> 2, wc = w & 3;
    const int fr = lane & 15, fq = lane >> 4;

    // XCD n-ownership: xcd = lin&7 owns n-tiles {2*xcd, 2*xcd+1}
    const int lin = blockIdx.x;
    const int xcd = lin & 7;
    const int idx = lin >> 3;            // 0..511
    const int mt  = idx >> 1;            // 0..255
    const size_t m0 = (size_t)mt * 256;
    const size_t n0 = (size_t)(xcd * 2 + (idx & 1)) * 256;

    // m-tile -> (b, t0): 256 rows = 4 t-values x 64 u-values, fixed b
    const int b  = mt >> 6;
    const int t0 = (mt & 63) << 2;

    // ---- A-staging thread mapping: thread -> (row r, k-half h) ----
    const int r  = tid >> 1;             // 0..255
    const int h  = tid & 1;              // elems [32h, 32h+32)
    const int tq = r >> 6;               // 0..3
    const int uu = r & 63;
    const int xr = (r & 7) << 4;         // row XOR swizzle (bytes)
    const u16* encrow = encln + (size_t)(b * T_ + t0 + tq) * J_ + 32 * h;
    const u16* decrow = decln + (size_t)(b * U_ + uu) * J_ + 32 * h;
    // LDS u16 offsets for the 4 swizzled 16B segments of this thread
    const int aw0 = r * BK + ((( 0 + 64 * h) ^ xr) >> 1);
    const int aw1 = r * BK + (((16 + 64 * h) ^ xr) >> 1);
    const int aw2 = r * BK + (((32 + 64 * h) ^ xr) >> 1);
    const int aw3 = r * BK + (((48 + 64 * h) ^ xr) >> 1);

    // ---- B-staging (gload_lds, pre-swizzled source) ----
    const int srow = lane >> 3;
    const int scol = ((lane & 7) * 16) ^ (srow << 4);
    const u16* bgbase = Bt + (n0 + w * 8 + srow) * (size_t)BIGK + (scol >> 1);
    const int ldst = (w * 8) * BK;

    f32x4 acc[8][4] = {};

#define STAGE_B(buf, c, k0)                                                        \
    __builtin_amdgcn_global_load_lds(                                              \
        (const __attribute__((address_space(1))) void*)(bgbase + (size_t)(c) * 64 * BIGK + (k0)), \
        (__attribute__((address_space(3))) void*)(&lds[buf][1][(c) * 64 * BK + ldst]), 16, 0, 0)

#define A_LOAD(kt)                                                                 \
    { const u16* ep = encrow + (size_t)(kt) * BK;                                  \
      const u16* dp = decrow + (size_t)(kt) * BK;                                  \
      ev0 = *(const uint4*)(ep);      dv0 = *(const uint4*)(dp);                   \
      ev1 = *(const uint4*)(ep + 8);  dv1 = *(const uint4*)(dp + 8);               \
      ev2 = *(const uint4*)(ep + 16); dv2 = *(const uint4*)(dp + 16);              \
      ev3 = *(const uint4*)(ep + 24); dv3 = *(const uint4*)(dp + 24); }

#define A_WRITE(buf)                                                               \
    { *(uint4*)(&lds[buf][0][aw0]) = joint4(ev0, dv0);                             \
      *(uint4*)(&lds[buf][0][aw1]) = joint4(ev1, dv1);                             \
      *(uint4*)(&lds[buf][0][aw2]) = joint4(ev2, dv2);                             \
      *(uint4*)(&lds[buf][0][aw3]) = joint4(ev3, dv3); }

#define RD_A(buf, mh, mi, kk)                                                      \
    (*reinterpret_cast<const bf16x8*>(&lds[buf][0][                                \
        (wr * 128 + (mh) * 64 + (mi) * 16 + fr) * BK +                             \
        ((((kk) * 64 + fq * 16) ^ ((fr & 7) << 4)) >> 1)]))
#define RD_B(buf, ni, kk)                                                          \
    (*reinterpret_cast<const bf16x8*>(&lds[buf][1][                                \
        (wc * 64 + (ni) * 16 + fr) * BK +                                          \
        ((((kk) * 64 + fq * 16) ^ ((fr & 7) << 4)) >> 1)]))

#define VM0   asm volatile("s_waitcnt vmcnt(0)" ::: "memory")
#define LGKM0 asm volatile("s_waitcnt lgkmcnt(0)" ::: "memory")

    {   // prologue: tile 0 into buf 0
        uint4 ev0, ev1, ev2, ev3, dv0, dv1, dv2, dv3;
        STAGE_B(0, 0, 0); STAGE_B(0, 1, 0); STAGE_B(0, 2, 0); STAGE_B(0, 3, 0);
        A_LOAD(0);
        A_WRITE(0);                        // compiler waits vmcnt for ev/dv
        VM0;                               // B loads resident
        LGKM0;                             // own ds_writes drained
        __builtin_amdgcn_s_barrier();
    }

    for (int t = 0; t < NT_; ++t) {
        const int cur = t & 1, nxt = cur ^ 1;
        const int kn = (t + 1) << 6;
        const bool pf = (t + 1 < NT_);
        bf16x8 af[4], b0[4], b1[4];
        uint4 ev0, ev1, ev2, ev3, dv0, dv1, dv2, dv3;

        // ---- phase 0: kk=0, m-low ----
#pragma unroll
        for (int i = 0; i < 4; ++i) af[i] = RD_A(cur, 0, i, 0);
#pragma unroll
        for (int j = 0; j < 4; ++j) b0[j] = RD_B(cur, j, 0);
        if (pf) { STAGE_B(nxt, 0, kn); STAGE_B(nxt, 1, kn); }
        __builtin_amdgcn_s_barrier();
        LGKM0;
        __builtin_amdgcn_s_setprio(1);
#pragma unroll
        for (int i = 0; i < 4; ++i)
#pragma unroll
            for (int j = 0; j < 4; ++j)
                acc[i][j] = __builtin_amdgcn_mfma_f32_16x16x32_bf16(af[i], b0[j], acc[i][j], 0, 0, 0);
        __builtin_amdgcn_s_setprio(0);
        __builtin_amdgcn_s_barrier();

        // ---- phase 1: kk=0, m-high ----
#pragma unroll
        for (int i = 0; i < 4; ++i) af[i] = RD_A(cur, 1, i, 0);
        if (pf) { STAGE_B(nxt, 2, kn); STAGE_B(nxt, 3, kn); }
        __builtin_amdgcn_s_barrier();
        LGKM0;
        __builtin_amdgcn_s_setprio(1);
#pragma unroll
        for (int i = 0; i < 4; ++i)
#pragma unroll
            for (int j = 0; j < 4; ++j)
                acc[4 + i][j] = __builtin_amdgcn_mfma_f32_16x16x32_bf16(af[i], b0[j], acc[4 + i][j], 0, 0, 0);
        __builtin_amdgcn_s_setprio(0);
        __builtin_amdgcn_s_barrier();

        // ---- phase 2: kk=1, m-low  (+ issue next A-tile's enc/dec loads) ----
#pragma unroll
        for (int i = 0; i < 4; ++i) af[i] = RD_A(cur, 0, i, 1);
#pragma unroll
        for (int j = 0; j < 4; ++j) b1[j] = RD_B(cur, j, 1);
        if (pf) A_LOAD(t + 1);
        __builtin_amdgcn_s_barrier();
        LGKM0;
        __builtin_amdgcn_s_setprio(1);
#pragma unroll
        for (int i = 0; i < 4; ++i)
#pragma unroll
            for (int j = 0; j < 4; ++j)
                acc[i][j] = __builtin_amdgcn_mfma_f32_16x16x32_bf16(af[i], b1[j], acc[i][j], 0, 0, 0);
        __builtin_amdgcn_s_setprio(0);
        __builtin_amdgcn_s_barrier();

        // ---- phase 3: kk=1, m-high (+ compute & ds_write next A-tile) ----
#pragma unroll
        for (int i = 0; i < 4; ++i) af[i] = RD_A(cur, 1, i, 1);
        if (pf) A_WRITE(nxt);              // compiler inserts counted vmcnt for ev/dv
        VM0;                               // drain next tile's B gloads (issued ph0/ph1)
        __builtin_amdgcn_s_barrier();
        LGKM0;                             // own af reads + A ds_writes drained
        __builtin_amdgcn_s_setprio(1);
#pragma unroll
        for (int i = 0; i < 4; ++i)
#pragma unroll
            for (int j = 0; j < 4; ++j)
                acc[4 + i][j] = __builtin_amdgcn_mfma_f32_16x16x32_bf16(af[i], b1[j], acc[4 + i][j], 0, 0, 0);
        __builtin_amdgcn_s_setprio(0);
        __builtin_amdgcn_s_barrier();      // nxt buf (A writes + B gloads) ready
    }

#undef STAGE_B
#undef A_LOAD
#undef A_WRITE
#undef RD_A
#undef RD_B
#undef VM0
#undef LGKM0

    // epilogue: nontemporal stores (don't wash L2/LLC)
    const size_t crow0 = m0 + wr * 128 + fq * 4;
    const size_t ccol0 = n0 + wc * 64 + fr;
#pragma unroll
    for (int ni = 0; ni < 4; ++ni) {
        const size_t col = ccol0 + ni * 16;
        const float bv = bias[col];
#pragma unroll
        for (int mi = 0; mi < 8; ++mi) {
            const size_t rbase = crow0 + mi * 16;
#pragma unroll
            for (int rr = 0; rr < 4; ++rr)
                __builtin_nontemporal_store(acc[mi][ni][rr] + bv,
                                            &C[(rbase + rr) * (size_t)BIGN + col]);
        }
    }
}

// ---------------- workspace layout (bytes) ----------------
static const size_t O_WOUT  = 0;                              // bf16 [4096][640]
static const size_t O_ENCLN = 5242880;                        // bf16 [B*T][J]
static const size_t O_DECLN = 6553600;                        // bf16 [B*U][J]
static const size_t O_ENCIN = 6881280;                        // bf16 [T*B][EENC]
static const size_t O_DECIN = 8978432;                        // bf16 [U*B][EDEC]
static const size_t O_WENC  = 9306112;                        // bf16 [J][EENC]
static const size_t O_WDEC  = 10616832;                       // bf16 [J][EDEC]
static const size_t O_EPROJ = 11436032;                       // f32  [T*B][J]
static const size_t O_DPROJ = 14057472;                       // f32  [U*B][J]
static const size_t WS_NEEDED = 14712832;

extern "C" void kernel_launch(void* const* d_in, const int* in_sizes, int n_in,
                              void* d_out, int out_size, void* d_ws, size_t ws_size,
                              hipStream_t stream) {
    const float* enc   = (const float*)d_in[0];
    const float* dec   = (const float*)d_in[1];
    const float* Wenc  = (const float*)d_in[2];
    const float* benc  = (const float*)d_in[3];
    const float* genc  = (const float*)d_in[4];
    const float* beenc = (const float*)d_in[5];
    const float* Wdec  = (const float*)d_in[6];
    const float* bdec  = (const float*)d_in[7];
    const float* gdec  = (const float*)d_in[8];
    const float* bedec = (const float*)d_in[9];
    const float* Wout  = (const float*)d_in[10];
    const float* bout  = (const float*)d_in[11];
    float* out = (float*)d_out;

    if (ws_size < WS_NEEDED) return;

    char* ws = (char*)d_ws;
    u16* wout_b = (u16*)(ws + O_WOUT);
    u16* encln  = (u16*)(ws + O_ENCLN);
    u16* decln  = (u16*)(ws + O_DECLN);
    u16* encin  = (u16*)(ws + O_ENCIN);
    u16* decin  = (u16*)(ws + O_DECIN);
    u16* wenc_b = (u16*)(ws + O_WENC);
    u16* wdec_b = (u16*)(ws + O_WDEC);
    float* eproj = (float*)(ws + O_EPROJ);
    float* dproj = (float*)(ws + O_DPROJ);

    // 1) bf16 converts
    cvt_bf16<<<1024, 256, 0, stream>>>(enc,  encin,  (T_ * B_ * EENC) / 4);
    cvt_bf16<<<160,  256, 0, stream>>>(dec,  decin,  (U_ * B_ * EDEC) / 4);
    cvt_bf16<<<640,  256, 0, stream>>>(Wenc, wenc_b, (J_ * EENC) / 4);
    cvt_bf16<<<400,  256, 0, stream>>>(Wdec, wdec_b, (J_ * EDEC) / 4);
    cvt_bf16<<<2560, 256, 0, stream>>>(Wout, wout_b, (V_ * J_) / 4);

    // 2) stage-1 projections (bias folded into LN)
    gemm_bt<<<dim3(J_ / 128, (T_ * B_) / 128), 256, 0, stream>>>(encin, wenc_b, eproj, nullptr, EENC, J_);
    gemm_bt<<<dim3(J_ / 128, (U_ * B_) / 128), 256, 0, stream>>>(decin, wdec_b, dproj, nullptr, EDEC, J_);

    // 3) LayerNorm (+bias +affine), transpose to [B, T/U, J], bf16
    ln_kernel<<<T_ * B_, 256, 0, stream>>>(eproj, benc, genc, beenc, encln, B_, T_);
    ln_kernel<<<U_ * B_, 256, 0, stream>>>(dproj, bdec, gdec, bedec, decln, B_, U_);

    // 4) fused joint + vocab projection -> d_out
    gemm_big<<<(B_ * T_ * U_ / 256) * (V_ / 256), 512, 0, stream>>>(encln, decln, wout_b, out, bout);
}

// Round 5
// 604.704 us; speedup vs baseline: 1.0212x; 1.0212x over previous
//
#include <hip/hip_runtime.h>
#include <stdint.h>

// Problem constants
#define T_    256
#define B_    4
#define U_    64
#define EENC  1024
#define EDEC  640
#define J_    640
#define V_    4096

typedef unsigned short u16;
typedef unsigned int   u32;
typedef __bf16 bf16x8 __attribute__((ext_vector_type(8)));
typedef short  s16x8  __attribute__((ext_vector_type(8)));
typedef float  f32x4  __attribute__((ext_vector_type(4)));

__device__ __forceinline__ u16 f2bf(float f) {
    u32 u = __builtin_bit_cast(u32, f);
    u = (u + 0x7FFFu + ((u >> 16) & 1u)) >> 16;
    return (u16)u;
}
__device__ __forceinline__ float bf2f(u16 b) {
    return __builtin_bit_cast(float, (u32)b << 16);
}

// ---------------- f32 -> bf16 convert (vectorized x4) ----------------
__global__ __launch_bounds__(256) void cvt_bf16(const float* __restrict__ src,
                                                u16* __restrict__ dst, int n4) {
    int i = blockIdx.x * 256 + threadIdx.x;
    if (i < n4) {
        float4 v = reinterpret_cast<const float4*>(src)[i];
        ushort4 o;
        o.x = f2bf(v.x); o.y = f2bf(v.y); o.z = f2bf(v.z); o.w = f2bf(v.w);
        reinterpret_cast<ushort4*>(dst)[i] = o;
    }
}

// ---------------- LayerNorm over J=640 + bias + affine, bf16 out, transposed ----------------
__global__ __launch_bounds__(256) void ln_kernel(const float* __restrict__ proj,
                                                 const float* __restrict__ bias,
                                                 const float* __restrict__ gamma,
                                                 const float* __restrict__ beta,
                                                 u16* __restrict__ out,
                                                 int BDIM, int OUTER) {
    int pr = blockIdx.x;
    int b = pr % BDIM, outer = pr / BDIM;
    const float* row = proj + (size_t)pr * J_;
    int tid = threadIdx.x;

    float x0 = row[tid] + bias[tid];
    float x1 = row[tid + 256] + bias[tid + 256];
    float x2 = 0.f;
    bool has3 = (tid < J_ - 512);
    if (has3) x2 = row[tid + 512] + bias[tid + 512];

    float s1 = x0 + x1 + x2;
    float s2 = x0 * x0 + x1 * x1 + x2 * x2;
    for (int off = 32; off; off >>= 1) {
        s1 += __shfl_down(s1, off, 64);
        s2 += __shfl_down(s2, off, 64);
    }
    __shared__ float ws1[4], ws2[4];
    int w = tid >> 6, lane = tid & 63;
    if (lane == 0) { ws1[w] = s1; ws2[w] = s2; }
    __syncthreads();
    float S1 = ws1[0] + ws1[1] + ws1[2] + ws1[3];
    float S2 = ws2[0] + ws2[1] + ws2[2] + ws2[3];
    float mu = S1 * (1.f / J_);
    float var = S2 * (1.f / J_) - mu * mu;
    float inv = 1.0f / sqrtf(var + 1e-5f);

    size_t orow = ((size_t)b * OUTER + outer) * J_;
    out[orow + tid]       = f2bf((x0 - mu) * inv * gamma[tid]       + beta[tid]);
    out[orow + tid + 256] = f2bf((x1 - mu) * inv * gamma[tid + 256] + beta[tid + 256]);
    if (has3)
        out[orow + tid + 512] = f2bf((x2 - mu) * inv * gamma[tid + 512] + beta[tid + 512]);
}

// ---------------- joint materialization: relu(enc[b,t,:] + dec[b,u,:]) -> bf16 [B*T*U][J] ----------------
__global__ __launch_bounds__(256) void joint_mat(const u16* __restrict__ encln,
                                                 const u16* __restrict__ decln,
                                                 u16* __restrict__ joint) {
    int g = blockIdx.x * 256 + threadIdx.x;
    int row = g / (J_ / 8);
    int jc = g - row * (J_ / 8);
    int b = row >> 14;
    int t = (row >> 6) & (T_ - 1);
    int u = row & (U_ - 1);
    s16x8 e = *reinterpret_cast<const s16x8*>(encln + ((size_t)(b * T_ + t)) * J_ + jc * 8);
    s16x8 d = *reinterpret_cast<const s16x8*>(decln + ((size_t)(b * U_ + u)) * J_ + jc * 8);
    s16x8 o;
#pragma unroll
    for (int k = 0; k < 8; ++k) {
        float v = bf2f((u16)e[k]) + bf2f((u16)d[k]);
        o[k] = (short)f2bf(fmaxf(v, 0.f));
    }
    *reinterpret_cast<s16x8*>(joint + (size_t)row * J_ + jc * 8) = o;
}

// ---------------- m97-structure 128x128 GEMM (stage-1 projections) ----------------
__global__ __launch_bounds__(256) void gemm_bt(const u16* __restrict__ A,
                                               const u16* __restrict__ Bt,
                                               float* __restrict__ C,
                                               const float* __restrict__ bias,
                                               int K, int ldc) {
    __shared__ u16 As[128 * 64];
    __shared__ u16 Bs[128 * 64];
    const int tid = threadIdx.x;
    const int w = tid >> 6, lane = tid & 63;
    const int wr = w >> 1, wc = w & 1;
    const size_t m0 = (size_t)blockIdx.y * 128;
    const size_t n0 = (size_t)blockIdx.x * 128;

    f32x4 acc[4][4] = {};

    const int l3 = lane >> 3;
    const int c8 = (lane & 7) * 8;
    const int nkt = K >> 6;

    for (int kt = 0; kt < nkt; ++kt) {
        if (kt) __syncthreads();
        const int k0 = kt << 6;
#pragma unroll
        for (int i = 0; i < 4; ++i) {
            const int c = w * 4 + i;
            const int r = c * 8 + l3;
            const u16* ga = A  + (m0 + r) * (size_t)K + k0 + c8;
            const u16* gb = Bt + (n0 + r) * (size_t)K + k0 + c8;
            __builtin_amdgcn_global_load_lds(
                (const __attribute__((address_space(1))) void*)ga,
                (__attribute__((address_space(3))) void*)(As + c * 512), 16, 0, 0);
            __builtin_amdgcn_global_load_lds(
                (const __attribute__((address_space(1))) void*)gb,
                (__attribute__((address_space(3))) void*)(Bs + c * 512), 16, 0, 0);
        }
        __syncthreads();

#pragma unroll
        for (int kk = 0; kk < 2; ++kk) {
            bf16x8 af[4], bfr[4];
#pragma unroll
            for (int i = 0; i < 4; ++i) {
                int ra = wr * 64 + i * 16 + (lane & 15);
                af[i] = *reinterpret_cast<const bf16x8*>(As + ra * 64 + kk * 32 + (lane >> 4) * 8);
                int rb = wc * 64 + i * 16 + (lane & 15);
                bfr[i] = *reinterpret_cast<const bf16x8*>(Bs + rb * 64 + kk * 32 + (lane >> 4) * 8);
            }
#pragma unroll
            for (int i = 0; i < 4; ++i)
#pragma unroll
                for (int j = 0; j < 4; ++j)
                    acc[i][j] = __builtin_amdgcn_mfma_f32_16x16x32_bf16(af[i], bfr[j], acc[i][j], 0, 0, 0);
        }
    }

    const int r4 = (lane >> 4) * 4;
    const int cl = lane & 15;
#pragma unroll
    for (int i = 0; i < 4; ++i) {
#pragma unroll
        for (int j = 0; j < 4; ++j) {
            size_t grow = m0 + wr * 64 + i * 16 + r4;
            size_t gcol = n0 + wc * 64 + j * 16 + cl;
            float bv = bias ? bias[gcol] : 0.f;
#pragma unroll
            for (int r = 0; r < 4; ++r)
                C[(grow + r) * (size_t)ldc + gcol] = acc[i][j][r] + bv;
        }
    }
}

// ---------------- 256x256 8-phase bf16 GEMM for the vocab projection ----------------
// M=65536, N=4096, K=640. 512 threads = 8 waves (2Mx4N), per-wave 128x64 out.
// T2 swizzle (linear gload_lds dest + pre-swizzled global src + swizzled ds_read).
// T4 counted vmcnt: issue order per tile = B0,B1,B2,B3,A0,A2,A1,A3 spread over
// phases; only vmcnt(2) waits (end-ph0 + boundary), never drain-to-0 mid-loop.
// Grid: XCD owns 2 n-tiles (B L2-resident); A-panel shared by the n-pair.
// Epilogue: REGULAR cached stores (L2 merges 64B halves into full lines,
// background writeback overlaps the next wg's K-loop). [R5 change vs R3's nt]
#define BK   64
#define BIGK 640
#define BIGN 4096
#define NT_  (BIGK / BK)

__global__ __launch_bounds__(512, 2) void gemm_big(const u16* __restrict__ A,
                                                   const u16* __restrict__ Bt,
                                                   float* __restrict__ C,
                                                   const float* __restrict__ bias) {
    __shared__ u16 lds[2][2][256 * BK];   // [buf][0=A,1=B]; 128 KiB

    const int tid = threadIdx.x;
    const int w = tid >> 6, lane = tid & 63;
    const int wr = w >> 2, wc = w & 3;
    const int fr = lane & 15, fq = lane >> 4;

    // XCD n-ownership: xcd = lin&7 owns n-tiles {2*xcd, 2*xcd+1}.
    const int lin = blockIdx.x;
    const int xcd = lin & 7;
    const int idx = lin >> 3;            // 0..511
    const size_t m0 = (size_t)(idx >> 1) * 256;
    const size_t n0 = (size_t)(xcd * 2 + (idx & 1)) * 256;

    // staging: chunk c = 64 rows of one operand; wave w stages rows c*64+w*8..+7.
    // LDS dest linear; global source col pre-swizzled (T2 involution).
    const int srow = lane >> 3;
    const int scol = ((lane & 7) * 16) ^ (srow << 4);
    const u16* agbase = A  + (m0 + w * 8 + srow) * (size_t)BIGK + (scol >> 1);
    const u16* bgbase = Bt + (n0 + w * 8 + srow) * (size_t)BIGK + (scol >> 1);
    const int ldst = (w * 8) * BK;

    f32x4 acc[8][4] = {};

#define STAGE_A(buf, c, k0)                                                        \
    __builtin_amdgcn_global_load_lds(                                              \
        (const __attribute__((address_space(1))) void*)(agbase + (size_t)(c) * 64 * BIGK + (k0)), \
        (__attribute__((address_space(3))) void*)(&lds[buf][0][(c) * 64 * BK + ldst]), 16, 0, 0)
#define STAGE_B(buf, c, k0)                                                        \
    __builtin_amdgcn_global_load_lds(                                              \
        (const __attribute__((address_space(1))) void*)(bgbase + (size_t)(c) * 64 * BIGK + (k0)), \
        (__attribute__((address_space(3))) void*)(&lds[buf][1][(c) * 64 * BK + ldst]), 16, 0, 0)

#define RD_A(buf, mh, mi, kk)                                                      \
    (*reinterpret_cast<const bf16x8*>(&lds[buf][0][                                \
        (wr * 128 + (mh) * 64 + (mi) * 16 + fr) * BK +                             \
        ((((kk) * 64 + fq * 16) ^ ((fr & 7) << 4)) >> 1)]))
#define RD_B(buf, ni, kk)                                                          \
    (*reinterpret_cast<const bf16x8*>(&lds[buf][1][                                \
        (wc * 64 + (ni) * 16 + fr) * BK +                                          \
        ((((kk) * 64 + fq * 16) ^ ((fr & 7) << 4)) >> 1)]))

#define WAIT2 asm volatile("s_waitcnt vmcnt(2)" ::: "memory")
#define WAIT0 asm volatile("s_waitcnt vmcnt(0)" ::: "memory")
#define LGKM0 asm volatile("s_waitcnt lgkmcnt(0)" ::: "memory")

    // prologue: tile 0, issue order B0..B3, A0, A2, A1, A3
    STAGE_B(0, 0, 0); STAGE_B(0, 1, 0); STAGE_B(0, 2, 0); STAGE_B(0, 3, 0);
    STAGE_A(0, 0, 0); STAGE_A(0, 2, 0); STAGE_A(0, 1, 0); STAGE_A(0, 3, 0);
    WAIT2;                                 // B*,A0,A2 resident; A1,A3 in flight
    __builtin_amdgcn_s_barrier();

    for (int t = 0; t < NT_; ++t) {
        const int cur = t & 1, nxt = cur ^ 1;
        const int kn = (t + 1) << 6;
        const bool pf = (t + 1 < NT_);
        bf16x8 af[4], b0[4], b1[4];

        // ---- phase 0: kk=0, m-low (reads B0-3 + A0/A2) ----
#pragma unroll
        for (int i = 0; i < 4; ++i) af[i] = RD_A(cur, 0, i, 0);
#pragma unroll
        for (int j = 0; j < 4; ++j) b0[j] = RD_B(cur, j, 0);
        if (pf) { STAGE_B(nxt, 0, kn); STAGE_B(nxt, 1, kn); }
        __builtin_amdgcn_s_barrier();
        LGKM0;
        __builtin_amdgcn_s_setprio(1);
#pragma unroll
        for (int i = 0; i < 4; ++i)
#pragma unroll
            for (int j = 0; j < 4; ++j)
                acc[i][j] = __builtin_amdgcn_mfma_f32_16x16x32_bf16(af[i], b0[j], acc[i][j], 0, 0, 0);
        __builtin_amdgcn_s_setprio(0);
        if (pf) WAIT2; else WAIT0;        // drain cur's A1,A3 (keep next B0,B1 in flight)
        __builtin_amdgcn_s_barrier();

        // ---- phase 1: kk=0, m-high (reads A1/A3) ----
#pragma unroll
        for (int i = 0; i < 4; ++i) af[i] = RD_A(cur, 1, i, 0);
        if (pf) { STAGE_B(nxt, 2, kn); STAGE_B(nxt, 3, kn); }
        __builtin_amdgcn_s_barrier();
        LGKM0;
        __builtin_amdgcn_s_setprio(1);
#pragma unroll
        for (int i = 0; i < 4; ++i)
#pragma unroll
            for (int j = 0; j < 4; ++j)
                acc[4 + i][j] = __builtin_amdgcn_mfma_f32_16x16x32_bf16(af[i], b0[j], acc[4 + i][j], 0, 0, 0);
        __builtin_amdgcn_s_setprio(0);
        __builtin_amdgcn_s_barrier();

        // ---- phase 2: kk=1, m-low (chunks already resident) ----
#pragma unroll
        for (int i = 0; i < 4; ++i) af[i] = RD_A(cur, 0, i, 1);
#pragma unroll
        for (int j = 0; j < 4; ++j) b1[j] = RD_B(cur, j, 1);
        if (pf) { STAGE_A(nxt, 0, kn); STAGE_A(nxt, 2, kn); }
        __builtin_amdgcn_s_barrier();
        LGKM0;
        __builtin_amdgcn_s_setprio(1);
#pragma unroll
        for (int i = 0; i < 4; ++i)
#pragma unroll
            for (int j = 0; j < 4; ++j)
                acc[i][j] = __builtin_amdgcn_mfma_f32_16x16x32_bf16(af[i], b1[j], acc[i][j], 0, 0, 0);
        __builtin_amdgcn_s_setprio(0);
        __builtin_amdgcn_s_barrier();

        // ---- phase 3: kk=1, m-high ----
#pragma unroll
        for (int i = 0; i < 4; ++i) af[i] = RD_A(cur, 1, i, 1);
        if (pf) { STAGE_A(nxt, 1, kn); STAGE_A(nxt, 3, kn); }
        __builtin_amdgcn_s_barrier();
        LGKM0;
        __builtin_amdgcn_s_setprio(1);
#pragma unroll
        for (int i = 0; i < 4; ++i)
#pragma unroll
            for (int j = 0; j < 4; ++j)
                acc[4 + i][j] = __builtin_amdgcn_mfma_f32_16x16x32_bf16(af[i], b1[j], acc[4 + i][j], 0, 0, 0);
        __builtin_amdgcn_s_setprio(0);
        if (pf) WAIT2;                    // next tile's B*,A0,A2 done; A1,A3 stay in flight
        __builtin_amdgcn_s_barrier();
    }

#undef STAGE_A
#undef STAGE_B
#undef RD_A
#undef RD_B
#undef WAIT2
#undef WAIT0
#undef LGKM0

    // epilogue: regular cached stores — L2 merges the 64B wave segments into
    // full 128B lines; writeback to HBM streams in background under the next
    // wg's K-loop. (nt variant measured R3=533; this isolates store mode.)
    const size_t crow0 = m0 + wr * 128 + fq * 4;
    const size_t ccol0 = n0 + wc * 64 + fr;
#pragma unroll
    for (int ni = 0; ni < 4; ++ni) {
        const size_t col = ccol0 + ni * 16;
        const float bv = bias[col];
#pragma unroll
        for (int mi = 0; mi < 8; ++mi) {
            const size_t rbase = crow0 + mi * 16;
#pragma unroll
            for (int r = 0; r < 4; ++r)
                C[(rbase + r) * (size_t)BIGN + col] = acc[mi][ni][r] + bv;
        }
    }
}

// ---------------- workspace layout (bytes) ----------------
static const size_t O_JOINT = 0;                              // bf16 [65536][640]
static const size_t O_WOUT  = 83886080;                       // bf16 [4096][640]
static const size_t O_ENCLN = 89128960;                       // bf16 [B*T][J]
static const size_t O_DECLN = 90439680;                       // bf16 [B*U][J]
static const size_t O_ENCIN = 90767360;                       // bf16 [T*B][EENC]
static const size_t O_DECIN = 92864512;                       // bf16 [U*B][EDEC]
static const size_t O_WENC  = 93192192;                       // bf16 [J][EENC]
static const size_t O_WDEC  = 94502912;                       // bf16 [J][EDEC]
static const size_t O_EPROJ = 95322112;                       // f32  [T*B][J]
static const size_t O_DPROJ = 97943552;                       // f32  [U*B][J]
static const size_t WS_NEEDED = 98598912;

extern "C" void kernel_launch(void* const* d_in, const int* in_sizes, int n_in,
                              void* d_out, int out_size, void* d_ws, size_t ws_size,
                              hipStream_t stream) {
    const float* enc   = (const float*)d_in[0];
    const float* dec   = (const float*)d_in[1];
    const float* Wenc  = (const float*)d_in[2];
    const float* benc  = (const float*)d_in[3];
    const float* genc  = (const float*)d_in[4];
    const float* beenc = (const float*)d_in[5];
    const float* Wdec  = (const float*)d_in[6];
    const float* bdec  = (const float*)d_in[7];
    const float* gdec  = (const float*)d_in[8];
    const float* bedec = (const float*)d_in[9];
    const float* Wout  = (const float*)d_in[10];
    const float* bout  = (const float*)d_in[11];
    float* out = (float*)d_out;

    if (ws_size < WS_NEEDED) return;

    char* ws = (char*)d_ws;
    u16* joint  = (u16*)(ws + O_JOINT);
    u16* wout_b = (u16*)(ws + O_WOUT);
    u16* encln  = (u16*)(ws + O_ENCLN);
    u16* decln  = (u16*)(ws + O_DECLN);
    u16* encin  = (u16*)(ws + O_ENCIN);
    u16* decin  = (u16*)(ws + O_DECIN);
    u16* wenc_b = (u16*)(ws + O_WENC);
    u16* wdec_b = (u16*)(ws + O_WDEC);
    float* eproj = (float*)(ws + O_EPROJ);
    float* dproj = (float*)(ws + O_DPROJ);

    // 1) bf16 converts
    cvt_bf16<<<1024, 256, 0, stream>>>(enc,  encin,  (T_ * B_ * EENC) / 4);
    cvt_bf16<<<160,  256, 0, stream>>>(dec,  decin,  (U_ * B_ * EDEC) / 4);
    cvt_bf16<<<640,  256, 0, stream>>>(Wenc, wenc_b, (J_ * EENC) / 4);
    cvt_bf16<<<400,  256, 0, stream>>>(Wdec, wdec_b, (J_ * EDEC) / 4);
    cvt_bf16<<<2560, 256, 0, stream>>>(Wout, wout_b, (V_ * J_) / 4);

    // 2) stage-1 projections (bias folded into LN)
    gemm_bt<<<dim3(J_ / 128, (T_ * B_) / 128), 256, 0, stream>>>(encin, wenc_b, eproj, nullptr, EENC, J_);
    gemm_bt<<<dim3(J_ / 128, (U_ * B_) / 128), 256, 0, stream>>>(decin, wdec_b, dproj, nullptr, EDEC, J_);

    // 3) LayerNorm (+bias +affine), transpose to [B, T/U, J], bf16
    ln_kernel<<<T_ * B_, 256, 0, stream>>>(eproj, benc, genc, beenc, encln, B_, T_);
    ln_kernel<<<U_ * B_, 256, 0, stream>>>(dproj, bdec, gdec, bedec, decln, B_, U_);

    // 4) joint = relu(enc + dec) materialized bf16 [B*T*U][J]
    joint_mat<<<(B_ * T_ * U_ * (J_ / 8)) / 256, 256, 0, stream>>>(encln, decln, joint);

    // 5) vocab projection: [65536, 640] x [640, 4096]^T + b_out -> d_out
    gemm_big<<<(B_ * T_ * U_ / 256) * (V_ / 256), 512, 0, stream>>>(joint, wout_b, out, bout);
}

// Round 6
// 503.356 us; speedup vs baseline: 1.2269x; 1.2013x over previous
//
#include <hip/hip_runtime.h>
#include <stdint.h>

// Problem constants
#define T_    256
#define B_    4
#define U_    64
#define EENC  1024
#define EDEC  640
#define J_    640
#define V_    4096

typedef unsigned short u16;
typedef unsigned int   u32;
typedef __bf16 bf16x8 __attribute__((ext_vector_type(8)));
typedef short  s16x8  __attribute__((ext_vector_type(8)));
typedef float  f32x4  __attribute__((ext_vector_type(4)));

__device__ __forceinline__ u16 f2bf(float f) {
    u32 u = __builtin_bit_cast(u32, f);
    u = (u + 0x7FFFu + ((u >> 16) & 1u)) >> 16;
    return (u16)u;
}
__device__ __forceinline__ float bf2f(u16 b) {
    return __builtin_bit_cast(float, (u32)b << 16);
}

// ---------------- f32 -> bf16 convert (vectorized x4) ----------------
__global__ __launch_bounds__(256) void cvt_bf16(const float* __restrict__ src,
                                                u16* __restrict__ dst, int n4) {
    int i = blockIdx.x * 256 + threadIdx.x;
    if (i < n4) {
        float4 v = reinterpret_cast<const float4*>(src)[i];
        ushort4 o;
        o.x = f2bf(v.x); o.y = f2bf(v.y); o.z = f2bf(v.z); o.w = f2bf(v.w);
        reinterpret_cast<ushort4*>(dst)[i] = o;
    }
}

// ---------------- LayerNorm over J=640 + bias + affine, bf16 out, transposed ----------------
__global__ __launch_bounds__(256) void ln_kernel(const float* __restrict__ proj,
                                                 const float* __restrict__ bias,
                                                 const float* __restrict__ gamma,
                                                 const float* __restrict__ beta,
                                                 u16* __restrict__ out,
                                                 int BDIM, int OUTER) {
    int pr = blockIdx.x;
    int b = pr % BDIM, outer = pr / BDIM;
    const float* row = proj + (size_t)pr * J_;
    int tid = threadIdx.x;

    float x0 = row[tid] + bias[tid];
    float x1 = row[tid + 256] + bias[tid + 256];
    float x2 = 0.f;
    bool has3 = (tid < J_ - 512);
    if (has3) x2 = row[tid + 512] + bias[tid + 512];

    float s1 = x0 + x1 + x2;
    float s2 = x0 * x0 + x1 * x1 + x2 * x2;
    for (int off = 32; off; off >>= 1) {
        s1 += __shfl_down(s1, off, 64);
        s2 += __shfl_down(s2, off, 64);
    }
    __shared__ float ws1[4], ws2[4];
    int w = tid >> 6, lane = tid & 63;
    if (lane == 0) { ws1[w] = s1; ws2[w] = s2; }
    __syncthreads();
    float S1 = ws1[0] + ws1[1] + ws1[2] + ws1[3];
    float S2 = ws2[0] + ws2[1] + ws2[2] + ws2[3];
    float mu = S1 * (1.f / J_);
    float var = S2 * (1.f / J_) - mu * mu;
    float inv = 1.0f / sqrtf(var + 1e-5f);

    size_t orow = ((size_t)b * OUTER + outer) * J_;
    out[orow + tid]       = f2bf((x0 - mu) * inv * gamma[tid]       + beta[tid]);
    out[orow + tid + 256] = f2bf((x1 - mu) * inv * gamma[tid + 256] + beta[tid + 256]);
    if (has3)
        out[orow + tid + 512] = f2bf((x2 - mu) * inv * gamma[tid + 512] + beta[tid + 512]);
}

// ---------------- joint materialization: relu(enc[b,t,:] + dec[b,u,:]) -> bf16 [B*T*U][J] ----------------
__global__ __launch_bounds__(256) void joint_mat(const u16* __restrict__ encln,
                                                 const u16* __restrict__ decln,
                                                 u16* __restrict__ joint) {
    int g = blockIdx.x * 256 + threadIdx.x;
    int row = g / (J_ / 8);
    int jc = g - row * (J_ / 8);
    int b = row >> 14;
    int t = (row >> 6) & (T_ - 1);
    int u = row & (U_ - 1);
    s16x8 e = *reinterpret_cast<const s16x8*>(encln + ((size_t)(b * T_ + t)) * J_ + jc * 8);
    s16x8 d = *reinterpret_cast<const s16x8*>(decln + ((size_t)(b * U_ + u)) * J_ + jc * 8);
    s16x8 o;
#pragma unroll
    for (int k = 0; k < 8; ++k) {
        float v = bf2f((u16)e[k]) + bf2f((u16)d[k]);
        o[k] = (short)f2bf(fmaxf(v, 0.f));
    }
    *reinterpret_cast<s16x8*>(joint + (size_t)row * J_ + jc * 8) = o;
}

// ---------------- m97-structure 128x128 GEMM (stage-1 projections) ----------------
__global__ __launch_bounds__(256) void gemm_bt(const u16* __restrict__ A,
                                               const u16* __restrict__ Bt,
                                               float* __restrict__ C,
                                               const float* __restrict__ bias,
                                               int K, int ldc) {
    __shared__ u16 As[128 * 64];
    __shared__ u16 Bs[128 * 64];
    const int tid = threadIdx.x;
    const int w = tid >> 6, lane = tid & 63;
    const int wr = w >> 1, wc = w & 1;
    const size_t m0 = (size_t)blockIdx.y * 128;
    const size_t n0 = (size_t)blockIdx.x * 128;

    f32x4 acc[4][4] = {};

    const int l3 = lane >> 3;
    const int c8 = (lane & 7) * 8;
    const int nkt = K >> 6;

    for (int kt = 0; kt < nkt; ++kt) {
        if (kt) __syncthreads();
        const int k0 = kt << 6;
#pragma unroll
        for (int i = 0; i < 4; ++i) {
            const int c = w * 4 + i;
            const int r = c * 8 + l3;
            const u16* ga = A  + (m0 + r) * (size_t)K + k0 + c8;
            const u16* gb = Bt + (n0 + r) * (size_t)K + k0 + c8;
            __builtin_amdgcn_global_load_lds(
                (const __attribute__((address_space(1))) void*)ga,
                (__attribute__((address_space(3))) void*)(As + c * 512), 16, 0, 0);
            __builtin_amdgcn_global_load_lds(
                (const __attribute__((address_space(1))) void*)gb,
                (__attribute__((address_space(3))) void*)(Bs + c * 512), 16, 0, 0);
        }
        __syncthreads();

#pragma unroll
        for (int kk = 0; kk < 2; ++kk) {
            bf16x8 af[4], bfr[4];
#pragma unroll
            for (int i = 0; i < 4; ++i) {
                int ra = wr * 64 + i * 16 + (lane & 15);
                af[i] = *reinterpret_cast<const bf16x8*>(As + ra * 64 + kk * 32 + (lane >> 4) * 8);
                int rb = wc * 64 + i * 16 + (lane & 15);
                bfr[i] = *reinterpret_cast<const bf16x8*>(Bs + rb * 64 + kk * 32 + (lane >> 4) * 8);
            }
#pragma unroll
            for (int i = 0; i < 4; ++i)
#pragma unroll
                for (int j = 0; j < 4; ++j)
                    acc[i][j] = __builtin_amdgcn_mfma_f32_16x16x32_bf16(af[i], bfr[j], acc[i][j], 0, 0, 0);
        }
    }

    const int r4 = (lane >> 4) * 4;
    const int cl = lane & 15;
#pragma unroll
    for (int i = 0; i < 4; ++i) {
#pragma unroll
        for (int j = 0; j < 4; ++j) {
            size_t grow = m0 + wr * 64 + i * 16 + r4;
            size_t gcol = n0 + wc * 64 + j * 16 + cl;
            float bv = bias ? bias[gcol] : 0.f;
#pragma unroll
            for (int r = 0; r < 4; ++r)
                C[(grow + r) * (size_t)ldc + gcol] = acc[i][j][r] + bv;
        }
    }
}

// ---------------- vocab projection: 128x256 tile, BK=32, 2 wgs/CU ----------------
// M=65536, N=4096, K=640. 512 thr = 8 waves (2Mx4N), wave tile 64x64, acc[4][4]
// = 64 VGPR -> __launch_bounds__(512,4) caps at 128 VGPR -> 16 waves/CU
// (2 wgs/CU): one wg's nt-store drain overlaps the other's K-loop.
// LDS 48 KiB: dbuf A[128][32] + B[256][32], 2-bit XOR swizzle (4-way residual
// conflict, hidden under 4 waves/SIMD of MFMA). One barrier per K-tile; stage
// calls issued ~16 MFMA before their vmcnt wait. nt-stores (R3/R5 A/B winner).
#define BKS  32
#define BIGK 640
#define BIGN 4096
#define NTS  (BIGK / BKS)

__global__ __launch_bounds__(512, 4) void gemm_big(const u16* __restrict__ A,
                                                   const u16* __restrict__ Bt,
                                                   float* __restrict__ C,
                                                   const float* __restrict__ bias) {
    __shared__ u16 Abuf[2][128 * BKS];   // 16 KiB
    __shared__ u16 Bbuf[2][256 * BKS];   // 32 KiB

    const int tid = threadIdx.x;
    const int w = tid >> 6, lane = tid & 63;
    const int wr = w >> 2, wc = w & 3;
    const int fr = lane & 15, fq = lane >> 4;

    // XCD n-ownership: xcd = lin&7 owns n-tiles {2*xcd, 2*xcd+1}
    const int lin = blockIdx.x;
    const int xcd = lin & 7;
    const int idx = lin >> 3;            // 0..1023
    const size_t m0 = (size_t)(idx >> 1) * 128;
    const size_t n0 = (size_t)(xcd * 2 + (idx & 1)) * 256;

    // staging: thread tid covers LDS bytes [tid*16, tid*16+16) of each call
    // region -> (row = tid>>2, phys seg = tid&3). T2 involution: source seg =
    // phys ^ (row&3), so ds_read with the same XOR returns logical data.
    const int arow = tid >> 2;                 // 0..127
    const int aseg = (tid & 3) ^ (arow & 3);
    const u16* aga  = A + (m0 + arow) * (size_t)BIGK + aseg * 8;
    const int bseg = (tid & 3) ^ (arow & 3);   // (row+128)&3 == row&3
    const u16* bga0 = Bt + (n0 + arow) * (size_t)BIGK + bseg * 8;
    const u16* bga1 = bga0 + (size_t)128 * BIGK;
    const int sdst = w * 512;                  // u16: wave stripe in call region

    f32x4 acc[4][4] = {};

#define STAGE(buf, k0)                                                             \
    { __builtin_amdgcn_global_load_lds(                                            \
          (const __attribute__((address_space(1))) void*)(aga + (k0)),             \
          (__attribute__((address_space(3))) void*)(&Abuf[buf][sdst]), 16, 0, 0);  \
      __builtin_amdgcn_global_load_lds(                                            \
          (const __attribute__((address_space(1))) void*)(bga0 + (k0)),            \
          (__attribute__((address_space(3))) void*)(&Bbuf[buf][sdst]), 16, 0, 0);  \
      __builtin_amdgcn_global_load_lds(                                            \
          (const __attribute__((address_space(1))) void*)(bga1 + (k0)),            \
          (__attribute__((address_space(3))) void*)(&Bbuf[buf][4096 + sdst]), 16, 0, 0); }

    // ds_read: logical (row, colbyte=fq*16) -> physical colbyte ^ ((row&3)<<4)
#define RD_A(buf, mi)                                                              \
    (*reinterpret_cast<const bf16x8*>(&Abuf[buf][                                  \
        (wr * 64 + (mi) * 16 + fr) * BKS +                                         \
        (((fq * 16) ^ (((wr * 64 + (mi) * 16 + fr) & 3) << 4)) >> 1)]))
#define RD_B(buf, ni)                                                              \
    (*reinterpret_cast<const bf16x8*>(&Bbuf[buf][                                  \
        (wc * 64 + (ni) * 16 + fr) * BKS +                                         \
        (((fq * 16) ^ (((wc * 64 + (ni) * 16 + fr) & 3) << 4)) >> 1)]))

#define VM0   asm volatile("s_waitcnt vmcnt(0)" ::: "memory")
#define LGKM0 asm volatile("s_waitcnt lgkmcnt(0)" ::: "memory")

    // prologue: tile 0
    STAGE(0, 0);
    VM0;
    __builtin_amdgcn_s_barrier();

    for (int t = 0; t < NTS; ++t) {
        const int cur = t & 1, nxt = cur ^ 1;
        const bool pf = (t + 1 < NTS);
        bf16x8 af[4], bf[4];

#pragma unroll
        for (int i = 0; i < 4; ++i) af[i] = RD_A(cur, i);
#pragma unroll
        for (int j = 0; j < 4; ++j) bf[j] = RD_B(cur, j);
        if (pf) STAGE(nxt, (t + 1) * BKS);     // issued ~16 MFMA before the wait
        LGKM0;
        __builtin_amdgcn_s_setprio(1);
#pragma unroll
        for (int i = 0; i < 4; ++i)
#pragma unroll
            for (int j = 0; j < 4; ++j)
                acc[i][j] = __builtin_amdgcn_mfma_f32_16x16x32_bf16(af[i], bf[j], acc[i][j], 0, 0, 0);
        __builtin_amdgcn_s_setprio(0);
        if (pf) {
            VM0;                               // own 3 stage calls landed
            __builtin_amdgcn_s_barrier();      // all waves' stages landed
        }
    }

#undef STAGE
#undef RD_A
#undef RD_B
#undef VM0
#undef LGKM0

    // epilogue: nontemporal stores (R5 A/B: cached stores wash L2, -70us)
    const size_t crow0 = m0 + wr * 64 + fq * 4;
    const size_t ccol0 = n0 + wc * 64 + fr;
#pragma unroll
    for (int ni = 0; ni < 4; ++ni) {
        const size_t col = ccol0 + ni * 16;
        const float bv = bias[col];
#pragma unroll
        for (int mi = 0; mi < 4; ++mi) {
            const size_t rbase = crow0 + mi * 16;
#pragma unroll
            for (int r = 0; r < 4; ++r)
                __builtin_nontemporal_store(acc[mi][ni][r] + bv,
                                            &C[(rbase + r) * (size_t)BIGN + col]);
        }
    }
}

// ---------------- workspace layout (bytes) ----------------
static const size_t O_JOINT = 0;                              // bf16 [65536][640]
static const size_t O_WOUT  = 83886080;                       // bf16 [4096][640]
static const size_t O_ENCLN = 89128960;                       // bf16 [B*T][J]
static const size_t O_DECLN = 90439680;                       // bf16 [B*U][J]
static const size_t O_ENCIN = 90767360;                       // bf16 [T*B][EENC]
static const size_t O_DECIN = 92864512;                       // bf16 [U*B][EDEC]
static const size_t O_WENC  = 93192192;                       // bf16 [J][EENC]
static const size_t O_WDEC  = 94502912;                       // bf16 [J][EDEC]
static const size_t O_EPROJ = 95322112;                       // f32  [T*B][J]
static const size_t O_DPROJ = 97943552;                       // f32  [U*B][J]
static const size_t WS_NEEDED = 98598912;

extern "C" void kernel_launch(void* const* d_in, const int* in_sizes, int n_in,
                              void* d_out, int out_size, void* d_ws, size_t ws_size,
                              hipStream_t stream) {
    const float* enc   = (const float*)d_in[0];
    const float* dec   = (const float*)d_in[1];
    const float* Wenc  = (const float*)d_in[2];
    const float* benc  = (const float*)d_in[3];
    const float* genc  = (const float*)d_in[4];
    const float* beenc = (const float*)d_in[5];
    const float* Wdec  = (const float*)d_in[6];
    const float* bdec  = (const float*)d_in[7];
    const float* gdec  = (const float*)d_in[8];
    const float* bedec = (const float*)d_in[9];
    const float* Wout  = (const float*)d_in[10];
    const float* bout  = (const float*)d_in[11];
    float* out = (float*)d_out;

    if (ws_size < WS_NEEDED) return;

    char* ws = (char*)d_ws;
    u16* joint  = (u16*)(ws + O_JOINT);
    u16* wout_b = (u16*)(ws + O_WOUT);
    u16* encln  = (u16*)(ws + O_ENCLN);
    u16* decln  = (u16*)(ws + O_DECLN);
    u16* encin  = (u16*)(ws + O_ENCIN);
    u16* decin  = (u16*)(ws + O_DECIN);
    u16* wenc_b = (u16*)(ws + O_WENC);
    u16* wdec_b = (u16*)(ws + O_WDEC);
    float* eproj = (float*)(ws + O_EPROJ);
    float* dproj = (float*)(ws + O_DPROJ);

    // 1) bf16 converts
    cvt_bf16<<<1024, 256, 0, stream>>>(enc,  encin,  (T_ * B_ * EENC) / 4);
    cvt_bf16<<<160,  256, 0, stream>>>(dec,  decin,  (U_ * B_ * EDEC) / 4);
    cvt_bf16<<<640,  256, 0, stream>>>(Wenc, wenc_b, (J_ * EENC) / 4);
    cvt_bf16<<<400,  256, 0, stream>>>(Wdec, wdec_b, (J_ * EDEC) / 4);
    cvt_bf16<<<2560, 256, 0, stream>>>(Wout, wout_b, (V_ * J_) / 4);

    // 2) stage-1 projections (bias folded into LN)
    gemm_bt<<<dim3(J_ / 128, (T_ * B_) / 128), 256, 0, stream>>>(encin, wenc_b, eproj, nullptr, EENC, J_);
    gemm_bt<<<dim3(J_ / 128, (U_ * B_) / 128), 256, 0, stream>>>(decin, wdec_b, dproj, nullptr, EDEC, J_);

    // 3) LayerNorm (+bias +affine), transpose to [B, T/U, J], bf16
    ln_kernel<<<T_ * B_, 256, 0, stream>>>(eproj, benc, genc, beenc, encln, B_, T_);
    ln_kernel<<<U_ * B_, 256, 0, stream>>>(dproj, bdec, gdec, bedec, decln, B_, U_);

    // 4) joint = relu(enc + dec) materialized bf16 [B*T*U][J]
    joint_mat<<<(B_ * T_ * U_ * (J_ / 8)) / 256, 256, 0, stream>>>(encln, decln, joint);

    // 5) vocab projection: [65536, 640] x [640, 4096]^T + b_out -> d_out
    gemm_big<<<(B_ * T_ * U_ / 128) * (V_ / 256), 512, 0, stream>>>(joint, wout_b, out, bout);
}

// Round 7
// 502.857 us; speedup vs baseline: 1.2281x; 1.0010x over previous
//
#include <hip/hip_runtime.h>
#include <stdint.h>

// Problem constants
#define T_    256
#define B_    4
#define U_    64
#define EENC  1024
#define EDEC  640
#define J_    640
#define V_    4096

typedef unsigned short u16;
typedef unsigned int   u32;
typedef __bf16 bf16x8 __attribute__((ext_vector_type(8)));
typedef short  s16x8  __attribute__((ext_vector_type(8)));
typedef float  f32x4  __attribute__((ext_vector_type(4)));

__device__ __forceinline__ u16 f2bf(float f) {
    u32 u = __builtin_bit_cast(u32, f);
    u = (u + 0x7FFFu + ((u >> 16) & 1u)) >> 16;
    return (u16)u;
}
__device__ __forceinline__ float bf2f(u16 b) {
    return __builtin_bit_cast(float, (u32)b << 16);
}

// ---------------- f32 -> bf16 convert (vectorized x4) ----------------
__global__ __launch_bounds__(256) void cvt_bf16(const float* __restrict__ src,
                                                u16* __restrict__ dst, int n4) {
    int i = blockIdx.x * 256 + threadIdx.x;
    if (i < n4) {
        float4 v = reinterpret_cast<const float4*>(src)[i];
        ushort4 o;
        o.x = f2bf(v.x); o.y = f2bf(v.y); o.z = f2bf(v.z); o.w = f2bf(v.w);
        reinterpret_cast<ushort4*>(dst)[i] = o;
    }
}

// ---------------- LayerNorm over J=640 + bias + affine, bf16 out, transposed ----------------
__global__ __launch_bounds__(256) void ln_kernel(const float* __restrict__ proj,
                                                 const float* __restrict__ bias,
                                                 const float* __restrict__ gamma,
                                                 const float* __restrict__ beta,
                                                 u16* __restrict__ out,
                                                 int BDIM, int OUTER) {
    int pr = blockIdx.x;
    int b = pr % BDIM, outer = pr / BDIM;
    const float* row = proj + (size_t)pr * J_;
    int tid = threadIdx.x;

    float x0 = row[tid] + bias[tid];
    float x1 = row[tid + 256] + bias[tid + 256];
    float x2 = 0.f;
    bool has3 = (tid < J_ - 512);
    if (has3) x2 = row[tid + 512] + bias[tid + 512];

    float s1 = x0 + x1 + x2;
    float s2 = x0 * x0 + x1 * x1 + x2 * x2;
    for (int off = 32; off; off >>= 1) {
        s1 += __shfl_down(s1, off, 64);
        s2 += __shfl_down(s2, off, 64);
    }
    __shared__ float ws1[4], ws2[4];
    int w = tid >> 6, lane = tid & 63;
    if (lane == 0) { ws1[w] = s1; ws2[w] = s2; }
    __syncthreads();
    float S1 = ws1[0] + ws1[1] + ws1[2] + ws1[3];
    float S2 = ws2[0] + ws2[1] + ws2[2] + ws2[3];
    float mu = S1 * (1.f / J_);
    float var = S2 * (1.f / J_) - mu * mu;
    float inv = 1.0f / sqrtf(var + 1e-5f);

    size_t orow = ((size_t)b * OUTER + outer) * J_;
    out[orow + tid]       = f2bf((x0 - mu) * inv * gamma[tid]       + beta[tid]);
    out[orow + tid + 256] = f2bf((x1 - mu) * inv * gamma[tid + 256] + beta[tid + 256]);
    if (has3)
        out[orow + tid + 512] = f2bf((x2 - mu) * inv * gamma[tid + 512] + beta[tid + 512]);
}

// ---------------- joint materialization: relu(enc[b,t,:] + dec[b,u,:]) -> bf16 [B*T*U][J] ----------------
__global__ __launch_bounds__(256) void joint_mat(const u16* __restrict__ encln,
                                                 const u16* __restrict__ decln,
                                                 u16* __restrict__ joint) {
    int g = blockIdx.x * 256 + threadIdx.x;
    int row = g / (J_ / 8);
    int jc = g - row * (J_ / 8);
    int b = row >> 14;
    int t = (row >> 6) & (T_ - 1);
    int u = row & (U_ - 1);
    s16x8 e = *reinterpret_cast<const s16x8*>(encln + ((size_t)(b * T_ + t)) * J_ + jc * 8);
    s16x8 d = *reinterpret_cast<const s16x8*>(decln + ((size_t)(b * U_ + u)) * J_ + jc * 8);
    s16x8 o;
#pragma unroll
    for (int k = 0; k < 8; ++k) {
        float v = bf2f((u16)e[k]) + bf2f((u16)d[k]);
        o[k] = (short)f2bf(fmaxf(v, 0.f));
    }
    *reinterpret_cast<s16x8*>(joint + (size_t)row * J_ + jc * 8) = o;
}

// ---------------- m97-structure 128x128 GEMM (stage-1 projections) ----------------
__global__ __launch_bounds__(256) void gemm_bt(const u16* __restrict__ A,
                                               const u16* __restrict__ Bt,
                                               float* __restrict__ C,
                                               const float* __restrict__ bias,
                                               int K, int ldc) {
    __shared__ u16 As[128 * 64];
    __shared__ u16 Bs[128 * 64];
    const int tid = threadIdx.x;
    const int w = tid >> 6, lane = tid & 63;
    const int wr = w >> 1, wc = w & 1;
    const size_t m0 = (size_t)blockIdx.y * 128;
    const size_t n0 = (size_t)blockIdx.x * 128;

    f32x4 acc[4][4] = {};

    const int l3 = lane >> 3;
    const int c8 = (lane & 7) * 8;
    const int nkt = K >> 6;

    for (int kt = 0; kt < nkt; ++kt) {
        if (kt) __syncthreads();
        const int k0 = kt << 6;
#pragma unroll
        for (int i = 0; i < 4; ++i) {
            const int c = w * 4 + i;
            const int r = c * 8 + l3;
            const u16* ga = A  + (m0 + r) * (size_t)K + k0 + c8;
            const u16* gb = Bt + (n0 + r) * (size_t)K + k0 + c8;
            __builtin_amdgcn_global_load_lds(
                (const __attribute__((address_space(1))) void*)ga,
                (__attribute__((address_space(3))) void*)(As + c * 512), 16, 0, 0);
            __builtin_amdgcn_global_load_lds(
                (const __attribute__((address_space(1))) void*)gb,
                (__attribute__((address_space(3))) void*)(Bs + c * 512), 16, 0, 0);
        }
        __syncthreads();

#pragma unroll
        for (int kk = 0; kk < 2; ++kk) {
            bf16x8 af[4], bfr[4];
#pragma unroll
            for (int i = 0; i < 4; ++i) {
                int ra = wr * 64 + i * 16 + (lane & 15);
                af[i] = *reinterpret_cast<const bf16x8*>(As + ra * 64 + kk * 32 + (lane >> 4) * 8);
                int rb = wc * 64 + i * 16 + (lane & 15);
                bfr[i] = *reinterpret_cast<const bf16x8*>(Bs + rb * 64 + kk * 32 + (lane >> 4) * 8);
            }
#pragma unroll
            for (int i = 0; i < 4; ++i)
#pragma unroll
                for (int j = 0; j < 4; ++j)
                    acc[i][j] = __builtin_amdgcn_mfma_f32_16x16x32_bf16(af[i], bfr[j], acc[i][j], 0, 0, 0);
        }
    }

    const int r4 = (lane >> 4) * 4;
    const int cl = lane & 15;
#pragma unroll
    for (int i = 0; i < 4; ++i) {
#pragma unroll
        for (int j = 0; j < 4; ++j) {
            size_t grow = m0 + wr * 64 + i * 16 + r4;
            size_t gcol = n0 + wc * 64 + j * 16 + cl;
            float bv = bias ? bias[gcol] : 0.f;
#pragma unroll
            for (int r = 0; r < 4; ++r)
                C[(grow + r) * (size_t)ldc + gcol] = acc[i][j][r] + bv;
        }
    }
}

// ---------------- vocab projection: 128x256 tile, BK=32, TRIPLE-buffered ----------------
// M=65536, N=4096, K=640. 512 thr = 8 waves (2Mx4N), wave tile 64x64, acc[4][4].
// __launch_bounds__(512,4) caps 128 VGPR -> 2 wgs/CU (LDS 72 KiB x2 = 144 <= 160).
// Ring of 3 K-tile buffers: stage set t+2 while computing t; end-of-tile wait is
// vmcnt(3) (drains set t+1, leaves t+2 in flight) -> ~1 full tile (~900 cyc) of
// latency cover for LLC A-reads, never drain-to-0 mid-loop (T4). nt-stores.
#define BKS  32
#define BIGK 640
#define BIGN 4096
#define NTS  (BIGK / BKS)
#define ASZ  (128 * BKS)   // u16 per A buffer
#define BSZ  (256 * BKS)   // u16 per B buffer

__global__ __launch_bounds__(512, 4) void gemm_big(const u16* __restrict__ A,
                                                   const u16* __restrict__ Bt,
                                                   float* __restrict__ C,
                                                   const float* __restrict__ bias) {
    __shared__ u16 Abuf[3 * ASZ];   // 24 KiB
    __shared__ u16 Bbuf[3 * BSZ];   // 48 KiB

    const int tid = threadIdx.x;
    const int w = tid >> 6, lane = tid & 63;
    const int wr = w >> 2, wc = w & 3;
    const int fr = lane & 15, fq = lane >> 4;

    // XCD n-ownership: xcd = lin&7 owns n-tiles {2*xcd, 2*xcd+1}
    const int lin = blockIdx.x;
    const int xcd = lin & 7;
    const int idx = lin >> 3;            // 0..1023
    const size_t m0 = (size_t)(idx >> 1) * 128;
    const size_t n0 = (size_t)(xcd * 2 + (idx & 1)) * 256;

    // staging: thread tid covers LDS bytes [tid*16, tid*16+16) of each region
    // -> (row = tid>>2, phys seg = tid&3). T2 involution: source seg = phys ^ (row&3).
    const int arow = tid >> 2;                 // 0..127
    const int aseg = (tid & 3) ^ (arow & 3);
    const u16* aga  = A + (m0 + arow) * (size_t)BIGK + aseg * 8;
    const u16* bga0 = Bt + (n0 + arow) * (size_t)BIGK + aseg * 8;
    const u16* bga1 = bga0 + (size_t)128 * BIGK;
    const int sdst = w * 512;                  // u16: wave stripe in region

    f32x4 acc[4][4] = {};

#define STAGE(bo, k0)                                                              \
    { __builtin_amdgcn_global_load_lds(                                            \
          (const __attribute__((address_space(1))) void*)(aga + (k0)),             \
          (__attribute__((address_space(3))) void*)(&Abuf[(bo) * ASZ + sdst]), 16, 0, 0); \
      __builtin_amdgcn_global_load_lds(                                            \
          (const __attribute__((address_space(1))) void*)(bga0 + (k0)),            \
          (__attribute__((address_space(3))) void*)(&Bbuf[(bo) * BSZ + sdst]), 16, 0, 0); \
      __builtin_amdgcn_global_load_lds(                                            \
          (const __attribute__((address_space(1))) void*)(bga1 + (k0)),            \
          (__attribute__((address_space(3))) void*)(&Bbuf[(bo) * BSZ + 4096 + sdst]), 16, 0, 0); }

    // ds_read: logical (row, colbyte=fq*16) -> physical colbyte ^ ((row&3)<<4)
#define RD_A(bo, mi)                                                               \
    (*reinterpret_cast<const bf16x8*>(&Abuf[(bo) * ASZ +                           \
        (wr * 64 + (mi) * 16 + fr) * BKS +                                         \
        (((fq * 16) ^ (((wr * 64 + (mi) * 16 + fr) & 3) << 4)) >> 1)]))
#define RD_B(bo, ni)                                                               \
    (*reinterpret_cast<const bf16x8*>(&Bbuf[(bo) * BSZ +                           \
        (wc * 64 + (ni) * 16 + fr) * BKS +                                         \
        (((fq * 16) ^ (((wc * 64 + (ni) * 16 + fr) & 3) << 4)) >> 1)]))

#define VM3   asm volatile("s_waitcnt vmcnt(3)" ::: "memory")
#define VM0   asm volatile("s_waitcnt vmcnt(0)" ::: "memory")
#define LGKM0 asm volatile("s_waitcnt lgkmcnt(0)" ::: "memory")

    // prologue: stage sets 0 and 1; wait for set 0 only (set 1 stays in flight)
    STAGE(0, 0);
    STAGE(1, BKS);
    VM3;
    __builtin_amdgcn_s_barrier();

    int cur = 0;
    for (int t = 0; t < NTS; ++t) {
        const bool pf2 = (t + 2 < NTS);
        int nx2 = cur + 2; if (nx2 >= 3) nx2 -= 3;
        bf16x8 af[4], bf[4];

#pragma unroll
        for (int i = 0; i < 4; ++i) af[i] = RD_A(cur, i);
#pragma unroll
        for (int j = 0; j < 4; ++j) bf[j] = RD_B(cur, j);
        if (pf2) STAGE(nx2, (t + 2) * BKS);
        LGKM0;
        __builtin_amdgcn_s_setprio(1);
#pragma unroll
        for (int i = 0; i < 4; ++i)
#pragma unroll
            for (int j = 0; j < 4; ++j)
                acc[i][j] = __builtin_amdgcn_mfma_f32_16x16x32_bf16(af[i], bf[j], acc[i][j], 0, 0, 0);
        __builtin_amdgcn_s_setprio(0);
        if (t + 1 < NTS) {
            if (pf2) VM3; else VM0;        // drain set t+1; keep t+2 in flight
            __builtin_amdgcn_s_barrier();
        }
        ++cur; if (cur >= 3) cur = 0;
    }

#undef STAGE
#undef RD_A
#undef RD_B
#undef VM3
#undef VM0
#undef LGKM0

    // epilogue: nontemporal stores (R5 A/B: cached stores wash L2/LLC)
    const size_t crow0 = m0 + wr * 64 + fq * 4;
    const size_t ccol0 = n0 + wc * 64 + fr;
#pragma unroll
    for (int ni = 0; ni < 4; ++ni) {
        const size_t col = ccol0 + ni * 16;
        const float bv = bias[col];
#pragma unroll
        for (int mi = 0; mi < 4; ++mi) {
            const size_t rbase = crow0 + mi * 16;
#pragma unroll
            for (int r = 0; r < 4; ++r)
                __builtin_nontemporal_store(acc[mi][ni][r] + bv,
                                            &C[(rbase + r) * (size_t)BIGN + col]);
        }
    }
}

// ---------------- workspace layout (bytes) ----------------
static const size_t O_JOINT = 0;                              // bf16 [65536][640]
static const size_t O_WOUT  = 83886080;                       // bf16 [4096][640]
static const size_t O_ENCLN = 89128960;                       // bf16 [B*T][J]
static const size_t O_DECLN = 90439680;                       // bf16 [B*U][J]
static const size_t O_ENCIN = 90767360;                       // bf16 [T*B][EENC]
static const size_t O_DECIN = 92864512;                       // bf16 [U*B][EDEC]
static const size_t O_WENC  = 93192192;                       // bf16 [J][EENC]
static const size_t O_WDEC  = 94502912;                       // bf16 [J][EDEC]
static const size_t O_EPROJ = 95322112;                       // f32  [T*B][J]
static const size_t O_DPROJ = 97943552;                       // f32  [U*B][J]
static const size_t WS_NEEDED = 98598912;

extern "C" void kernel_launch(void* const* d_in, const int* in_sizes, int n_in,
                              void* d_out, int out_size, void* d_ws, size_t ws_size,
                              hipStream_t stream) {
    const float* enc   = (const float*)d_in[0];
    const float* dec   = (const float*)d_in[1];
    const float* Wenc  = (const float*)d_in[2];
    const float* benc  = (const float*)d_in[3];
    const float* genc  = (const float*)d_in[4];
    const float* beenc = (const float*)d_in[5];
    const float* Wdec  = (const float*)d_in[6];
    const float* bdec  = (const float*)d_in[7];
    const float* gdec  = (const float*)d_in[8];
    const float* bedec = (const float*)d_in[9];
    const float* Wout  = (const float*)d_in[10];
    const float* bout  = (const float*)d_in[11];
    float* out = (float*)d_out;

    if (ws_size < WS_NEEDED) return;

    char* ws = (char*)d_ws;
    u16* joint  = (u16*)(ws + O_JOINT);
    u16* wout_b = (u16*)(ws + O_WOUT);
    u16* encln  = (u16*)(ws + O_ENCLN);
    u16* decln  = (u16*)(ws + O_DECLN);
    u16* encin  = (u16*)(ws + O_ENCIN);
    u16* decin  = (u16*)(ws + O_DECIN);
    u16* wenc_b = (u16*)(ws + O_WENC);
    u16* wdec_b = (u16*)(ws + O_WDEC);
    float* eproj = (float*)(ws + O_EPROJ);
    float* dproj = (float*)(ws + O_DPROJ);

    // 1) bf16 converts
    cvt_bf16<<<1024, 256, 0, stream>>>(enc,  encin,  (T_ * B_ * EENC) / 4);
    cvt_bf16<<<160,  256, 0, stream>>>(dec,  decin,  (U_ * B_ * EDEC) / 4);
    cvt_bf16<<<640,  256, 0, stream>>>(Wenc, wenc_b, (J_ * EENC) / 4);
    cvt_bf16<<<400,  256, 0, stream>>>(Wdec, wdec_b, (J_ * EDEC) / 4);
    cvt_bf16<<<2560, 256, 0, stream>>>(Wout, wout_b, (V_ * J_) / 4);

    // 2) stage-1 projections (bias folded into LN)
    gemm_bt<<<dim3(J_ / 128, (T_ * B_) / 128), 256, 0, stream>>>(encin, wenc_b, eproj, nullptr, EENC, J_);
    gemm_bt<<<dim3(J_ / 128, (U_ * B_) / 128), 256, 0, stream>>>(decin, wdec_b, dproj, nullptr, EDEC, J_);

    // 3) LayerNorm (+bias +affine), transpose to [B, T/U, J], bf16
    ln_kernel<<<T_ * B_, 256, 0, stream>>>(eproj, benc, genc, beenc, encln, B_, T_);
    ln_kernel<<<U_ * B_, 256, 0, stream>>>(dproj, bdec, gdec, bedec, decln, B_, U_);

    // 4) joint = relu(enc + dec) materialized bf16 [B*T*U][J]
    joint_mat<<<(B_ * T_ * U_ * (J_ / 8)) / 256, 256, 0, stream>>>(encln, decln, joint);

    // 5) vocab projection: [65536, 640] x [640, 4096]^T + b_out -> d_out
    gemm_big<<<(B_ * T_ * U_ / 128) * (V_ / 256), 512, 0, stream>>>(joint, wout_b, out, bout);
}

// Round 9
// 498.014 us; speedup vs baseline: 1.2400x; 1.0097x over previous
//
#include <hip/hip_runtime.h>
#include <stdint.h>

// Problem constants
#define T_    256
#define B_    4
#define U_    64
#define EENC  1024
#define EDEC  640
#define J_    640
#define V_    4096

typedef unsigned short u16;
typedef unsigned int   u32;
typedef __bf16 bf16x8 __attribute__((ext_vector_type(8)));
typedef short  s16x8  __attribute__((ext_vector_type(8)));
typedef float  f32x4  __attribute__((ext_vector_type(4)));

__device__ __forceinline__ u16 f2bf(float f) {
    u32 u = __builtin_bit_cast(u32, f);
    u = (u + 0x7FFFu + ((u >> 16) & 1u)) >> 16;
    return (u16)u;
}
__device__ __forceinline__ float bf2f(u16 b) {
    return __builtin_bit_cast(float, (u32)b << 16);
}

// ---------------- f32 -> bf16 convert (vectorized x4) ----------------
__global__ __launch_bounds__(256) void cvt_bf16(const float* __restrict__ src,
                                                u16* __restrict__ dst, int n4) {
    int i = blockIdx.x * 256 + threadIdx.x;
    if (i < n4) {
        float4 v = reinterpret_cast<const float4*>(src)[i];
        ushort4 o;
        o.x = f2bf(v.x); o.y = f2bf(v.y); o.z = f2bf(v.z); o.w = f2bf(v.w);
        reinterpret_cast<ushort4*>(dst)[i] = o;
    }
}

// ---------------- LayerNorm over J=640 + bias + affine, bf16 out, transposed ----------------
__global__ __launch_bounds__(256) void ln_kernel(const float* __restrict__ proj,
                                                 const float* __restrict__ bias,
                                                 const float* __restrict__ gamma,
                                                 const float* __restrict__ beta,
                                                 u16* __restrict__ out,
                                                 int BDIM, int OUTER) {
    int pr = blockIdx.x;
    int b = pr % BDIM, outer = pr / BDIM;
    const float* row = proj + (size_t)pr * J_;
    int tid = threadIdx.x;

    float x0 = row[tid] + bias[tid];
    float x1 = row[tid + 256] + bias[tid + 256];
    float x2 = 0.f;
    bool has3 = (tid < J_ - 512);
    if (has3) x2 = row[tid + 512] + bias[tid + 512];

    float s1 = x0 + x1 + x2;
    float s2 = x0 * x0 + x1 * x1 + x2 * x2;
    for (int off = 32; off; off >>= 1) {
        s1 += __shfl_down(s1, off, 64);
        s2 += __shfl_down(s2, off, 64);
    }
    __shared__ float ws1[4], ws2[4];
    int w = tid >> 6, lane = tid & 63;
    if (lane == 0) { ws1[w] = s1; ws2[w] = s2; }
    __syncthreads();
    float S1 = ws1[0] + ws1[1] + ws1[2] + ws1[3];
    float S2 = ws2[0] + ws2[1] + ws2[2] + ws2[3];
    float mu = S1 * (1.f / J_);
    float var = S2 * (1.f / J_) - mu * mu;
    float inv = 1.0f / sqrtf(var + 1e-5f);

    size_t orow = ((size_t)b * OUTER + outer) * J_;
    out[orow + tid]       = f2bf((x0 - mu) * inv * gamma[tid]       + beta[tid]);
    out[orow + tid + 256] = f2bf((x1 - mu) * inv * gamma[tid + 256] + beta[tid + 256]);
    if (has3)
        out[orow + tid + 512] = f2bf((x2 - mu) * inv * gamma[tid + 512] + beta[tid + 512]);
}

// ---------------- joint materialization: relu(enc[b,t,:] + dec[b,u,:]) -> bf16 [B*T*U][J] ----------------
__global__ __launch_bounds__(256) void joint_mat(const u16* __restrict__ encln,
                                                 const u16* __restrict__ decln,
                                                 u16* __restrict__ joint) {
    int g = blockIdx.x * 256 + threadIdx.x;
    int row = g / (J_ / 8);
    int jc = g - row * (J_ / 8);
    int b = row >> 14;
    int t = (row >> 6) & (T_ - 1);
    int u = row & (U_ - 1);
    s16x8 e = *reinterpret_cast<const s16x8*>(encln + ((size_t)(b * T_ + t)) * J_ + jc * 8);
    s16x8 d = *reinterpret_cast<const s16x8*>(decln + ((size_t)(b * U_ + u)) * J_ + jc * 8);
    s16x8 o;
#pragma unroll
    for (int k = 0; k < 8; ++k) {
        float v = bf2f((u16)e[k]) + bf2f((u16)d[k]);
        o[k] = (short)f2bf(fmaxf(v, 0.f));
    }
    *reinterpret_cast<s16x8*>(joint + (size_t)row * J_ + jc * 8) = o;
}

// ---------------- m97-structure 128x128 GEMM (stage-1 projections) ----------------
__global__ __launch_bounds__(256) void gemm_bt(const u16* __restrict__ A,
                                               const u16* __restrict__ Bt,
                                               float* __restrict__ C,
                                               const float* __restrict__ bias,
                                               int K, int ldc) {
    __shared__ u16 As[128 * 64];
    __shared__ u16 Bs[128 * 64];
    const int tid = threadIdx.x;
    const int w = tid >> 6, lane = tid & 63;
    const int wr = w >> 1, wc = w & 1;
    const size_t m0 = (size_t)blockIdx.y * 128;
    const size_t n0 = (size_t)blockIdx.x * 128;

    f32x4 acc[4][4] = {};

    const int l3 = lane >> 3;
    const int c8 = (lane & 7) * 8;
    const int nkt = K >> 6;

    for (int kt = 0; kt < nkt; ++kt) {
        if (kt) __syncthreads();
        const int k0 = kt << 6;
#pragma unroll
        for (int i = 0; i < 4; ++i) {
            const int c = w * 4 + i;
            const int r = c * 8 + l3;
            const u16* ga = A  + (m0 + r) * (size_t)K + k0 + c8;
            const u16* gb = Bt + (n0 + r) * (size_t)K + k0 + c8;
            __builtin_amdgcn_global_load_lds(
                (const __attribute__((address_space(1))) void*)ga,
                (__attribute__((address_space(3))) void*)(As + c * 512), 16, 0, 0);
            __builtin_amdgcn_global_load_lds(
                (const __attribute__((address_space(1))) void*)gb,
                (__attribute__((address_space(3))) void*)(Bs + c * 512), 16, 0, 0);
        }
        __syncthreads();

#pragma unroll
        for (int kk = 0; kk < 2; ++kk) {
            bf16x8 af[4], bfr[4];
#pragma unroll
            for (int i = 0; i < 4; ++i) {
                int ra = wr * 64 + i * 16 + (lane & 15);
                af[i] = *reinterpret_cast<const bf16x8*>(As + ra * 64 + kk * 32 + (lane >> 4) * 8);
                int rb = wc * 64 + i * 16 + (lane & 15);
                bfr[i] = *reinterpret_cast<const bf16x8*>(Bs + rb * 64 + kk * 32 + (lane >> 4) * 8);
            }
#pragma unroll
            for (int i = 0; i < 4; ++i)
#pragma unroll
                for (int j = 0; j < 4; ++j)
                    acc[i][j] = __builtin_amdgcn_mfma_f32_16x16x32_bf16(af[i], bfr[j], acc[i][j], 0, 0, 0);
        }
    }

    const int r4 = (lane >> 4) * 4;
    const int cl = lane & 15;
#pragma unroll
    for (int i = 0; i < 4; ++i) {
#pragma unroll
        for (int j = 0; j < 4; ++j) {
            size_t grow = m0 + wr * 64 + i * 16 + r4;
            size_t gcol = n0 + wc * 64 + j * 16 + cl;
            float bv = bias ? bias[gcol] : 0.f;
#pragma unroll
            for (int r = 0; r < 4; ++r)
                C[(grow + r) * (size_t)ldc + gcol] = acc[i][j][r] + bv;
        }
    }
}

// ---------------- vocab projection: 128x256 tile, BK=32, triple-buffered ----------------
// K-loop identical to R7. R8/R9 change: epilogue bounces the 128x256 f32 tile
// through LDS (two 64-row halves, stride-257 pad) so nt stores are f32x4 with
// 64-lane contiguity -> full 1 KB/instruction HBM bursts (fill-kernel pattern)
// instead of 64 B partial segments.
#define BKS  32
#define BIGK 640
#define BIGN 4096
#define NTS  (BIGK / BKS)
#define ASZ  (128 * BKS)   // u16 per A buffer
#define BSZ  (256 * BKS)   // u16 per B buffer

__global__ __launch_bounds__(512, 4) void gemm_big(const u16* __restrict__ A,
                                                   const u16* __restrict__ Bt,
                                                   float* __restrict__ C,
                                                   const float* __restrict__ bias) {
    __shared__ u16 shm[3 * ASZ + 3 * BSZ];   // 72 KiB (staging ring + epilogue bounce)

    const int tid = threadIdx.x;
    const int w = tid >> 6, lane = tid & 63;
    const int wr = w >> 2, wc = w & 3;
    const int fr = lane & 15, fq = lane >> 4;

    // XCD n-ownership: xcd = lin&7 owns n-tiles {2*xcd, 2*xcd+1}
    const int lin = blockIdx.x;
    const int xcd = lin & 7;
    const int idx = lin >> 3;            // 0..1023
    const size_t m0 = (size_t)(idx >> 1) * 128;
    const size_t n0 = (size_t)(xcd * 2 + (idx & 1)) * 256;

    // staging: thread tid covers LDS bytes [tid*16, tid*16+16) of each region
    // -> (row = tid>>2, phys seg = tid&3). T2 involution: source seg = phys ^ (row&3).
    const int arow = tid >> 2;                 // 0..127
    const int aseg = (tid & 3) ^ (arow & 3);
    const u16* aga  = A + (m0 + arow) * (size_t)BIGK + aseg * 8;
    const u16* bga0 = Bt + (n0 + arow) * (size_t)BIGK + aseg * 8;
    const u16* bga1 = bga0 + (size_t)128 * BIGK;
    const int sdst = w * 512;                  // u16: wave stripe in region

    f32x4 acc[4][4] = {};

#define STAGE(bo, k0)                                                              \
    { __builtin_amdgcn_global_load_lds(                                            \
          (const __attribute__((address_space(1))) void*)(aga + (k0)),             \
          (__attribute__((address_space(3))) void*)(&shm[(bo) * ASZ + sdst]), 16, 0, 0); \
      __builtin_amdgcn_global_load_lds(                                            \
          (const __attribute__((address_space(1))) void*)(bga0 + (k0)),            \
          (__attribute__((address_space(3))) void*)(&shm[3 * ASZ + (bo) * BSZ + sdst]), 16, 0, 0); \
      __builtin_amdgcn_global_load_lds(                                            \
          (const __attribute__((address_space(1))) void*)(bga1 + (k0)),            \
          (__attribute__((address_space(3))) void*)(&shm[3 * ASZ + (bo) * BSZ + 4096 + sdst]), 16, 0, 0); }

    // ds_read: logical (row, colbyte=fq*16) -> physical colbyte ^ ((row&3)<<4)
#define RD_A(bo, mi)                                                               \
    (*reinterpret_cast<const bf16x8*>(&shm[(bo) * ASZ +                            \
        (wr * 64 + (mi) * 16 + fr) * BKS +                                         \
        (((fq * 16) ^ (((wr * 64 + (mi) * 16 + fr) & 3) << 4)) >> 1)]))
#define RD_B(bo, ni)                                                               \
    (*reinterpret_cast<const bf16x8*>(&shm[3 * ASZ + (bo) * BSZ +                  \
        (wc * 64 + (ni) * 16 + fr) * BKS +                                         \
        (((fq * 16) ^ (((wc * 64 + (ni) * 16 + fr) & 3) << 4)) >> 1)]))

#define VM3   asm volatile("s_waitcnt vmcnt(3)" ::: "memory")
#define VM0   asm volatile("s_waitcnt vmcnt(0)" ::: "memory")
#define LGKM0 asm volatile("s_waitcnt lgkmcnt(0)" ::: "memory")

    // prologue: stage sets 0 and 1; wait for set 0 only (set 1 stays in flight)
    STAGE(0, 0);
    STAGE(1, BKS);
    VM3;
    __builtin_amdgcn_s_barrier();

    int cur = 0;
    for (int t = 0; t < NTS; ++t) {
        const bool pf2 = (t + 2 < NTS);
        int nx2 = cur + 2; if (nx2 >= 3) nx2 -= 3;
        bf16x8 af[4], bf[4];

#pragma unroll
        for (int i = 0; i < 4; ++i) af[i] = RD_A(cur, i);
#pragma unroll
        for (int j = 0; j < 4; ++j) bf[j] = RD_B(cur, j);
        if (pf2) STAGE(nx2, (t + 2) * BKS);
        LGKM0;
        __builtin_amdgcn_s_setprio(1);
#pragma unroll
        for (int i = 0; i < 4; ++i)
#pragma unroll
            for (int j = 0; j < 4; ++j)
                acc[i][j] = __builtin_amdgcn_mfma_f32_16x16x32_bf16(af[i], bf[j], acc[i][j], 0, 0, 0);
        __builtin_amdgcn_s_setprio(0);
        if (t + 1 < NTS) {
            if (pf2) VM3; else VM0;        // drain set t+1; keep t+2 in flight
            __builtin_amdgcn_s_barrier();
        }
        ++cur; if (cur >= 3) cur = 0;
    }

#undef STAGE
#undef RD_A
#undef RD_B
#undef VM3
#undef VM0
#undef LGKM0

    // ---- epilogue: LDS bounce -> contiguous f32x4 nt stores ----
    // bounce buffer: [64][257] f32 (65.8 KB, overlays the staging ring).
    // phase half=0: waves with wr==0 write rows 0..63 of the tile; all waves
    // then store 8 rows each as 64-lane f32x4 (1 KB/inst). half=1: wr==1 rows.
    float* bnc = reinterpret_cast<float*>(shm);
#pragma unroll
    for (int half = 0; half < 2; ++half) {
        __syncthreads();                    // prior phase reads / K-loop LDS use done
        if (wr == half) {
#pragma unroll
            for (int ni = 0; ni < 4; ++ni) {
                const int col = wc * 64 + ni * 16 + fr;
                const float bv = bias[n0 + col];
#pragma unroll
                for (int mi = 0; mi < 4; ++mi) {
                    const int lr = mi * 16 + fq * 4;
#pragma unroll
                    for (int r = 0; r < 4; ++r)
                        bnc[(lr + r) * 257 + col] = acc[mi][ni][r] + bv;
                }
            }
        }
        __syncthreads();
#pragma unroll
        for (int rr = 0; rr < 8; ++rr) {
            const int lrow = w * 8 + rr;
            const size_t grow = m0 + half * 64 + lrow;
            f32x4 v = *reinterpret_cast<const f32x4*>(&bnc[lrow * 257 + lane * 4]);
            __builtin_nontemporal_store(v,
                reinterpret_cast<f32x4*>(&C[grow * (size_t)BIGN + n0 + lane * 4]));
        }
    }
}

// ---------------- workspace layout (bytes) ----------------
static const size_t O_JOINT = 0;                              // bf16 [65536][640]
static const size_t O_WOUT  = 83886080;                       // bf16 [4096][640]
static const size_t O_ENCLN = 89128960;                       // bf16 [B*T][J]
static const size_t O_DECLN = 90439680;                       // bf16 [B*U][J]
static const size_t O_ENCIN = 90767360;                       // bf16 [T*B][EENC]
static const size_t O_DECIN = 92864512;                       // bf16 [U*B][EDEC]
static const size_t O_WENC  = 93192192;                       // bf16 [J][EENC]
static const size_t O_WDEC  = 94502912;                       // bf16 [J][EDEC]
static const size_t O_EPROJ = 95322112;                       // f32  [T*B][J]
static const size_t O_DPROJ = 97943552;                       // f32  [U*B][J]
static const size_t WS_NEEDED = 98598912;

extern "C" void kernel_launch(void* const* d_in, const int* in_sizes, int n_in,
                              void* d_out, int out_size, void* d_ws, size_t ws_size,
                              hipStream_t stream) {
    const float* enc   = (const float*)d_in[0];
    const float* dec   = (const float*)d_in[1];
    const float* Wenc  = (const float*)d_in[2];
    const float* benc  = (const float*)d_in[3];
    const float* genc  = (const float*)d_in[4];
    const float* beenc = (const float*)d_in[5];
    const float* Wdec  = (const float*)d_in[6];
    const float* bdec  = (const float*)d_in[7];
    const float* gdec  = (const float*)d_in[8];
    const float* bedec = (const float*)d_in[9];
    const float* Wout  = (const float*)d_in[10];
    const float* bout  = (const float*)d_in[11];
    float* out = (float*)d_out;

    if (ws_size < WS_NEEDED) return;

    char* ws = (char*)d_ws;
    u16* joint  = (u16*)(ws + O_JOINT);
    u16* wout_b = (u16*)(ws + O_WOUT);
    u16* encln  = (u16*)(ws + O_ENCLN);
    u16* decln  = (u16*)(ws + O_DECLN);
    u16* encin  = (u16*)(ws + O_ENCIN);
    u16* decin  = (u16*)(ws + O_DECIN);
    u16* wenc_b = (u16*)(ws + O_WENC);
    u16* wdec_b = (u16*)(ws + O_WDEC);
    float* eproj = (float*)(ws + O_EPROJ);
    float* dproj = (float*)(ws + O_DPROJ);

    // 1) bf16 converts
    cvt_bf16<<<1024, 256, 0, stream>>>(enc,  encin,  (T_ * B_ * EENC) / 4);
    cvt_bf16<<<160,  256, 0, stream>>>(dec,  decin,  (U_ * B_ * EDEC) / 4);
    cvt_bf16<<<640,  256, 0, stream>>>(Wenc, wenc_b, (J_ * EENC) / 4);
    cvt_bf16<<<400,  256, 0, stream>>>(Wdec, wdec_b, (J_ * EDEC) / 4);
    cvt_bf16<<<2560, 256, 0, stream>>>(Wout, wout_b, (V_ * J_) / 4);

    // 2) stage-1 projections (bias folded into LN)
    gemm_bt<<<dim3(J_ / 128, (T_ * B_) / 128), 256, 0, stream>>>(encin, wenc_b, eproj, nullptr, EENC, J_);
    gemm_bt<<<dim3(J_ / 128, (U_ * B_) / 128), 256, 0, stream>>>(decin, wdec_b, dproj, nullptr, EDEC, J_);

    // 3) LayerNorm (+bias +affine), transpose to [B, T/U, J], bf16
    ln_kernel<<<T_ * B_, 256, 0, stream>>>(eproj, benc, genc, beenc, encln, B_, T_);
    ln_kernel<<<U_ * B_, 256, 0, stream>>>(dproj, bdec, gdec, bedec, decln, B_, U_);

    // 4) joint = relu(enc + dec) materialized bf16 [B*T*U][J]
    joint_mat<<<(B_ * T_ * U_ * (J_ / 8)) / 256, 256, 0, stream>>>(encln, decln, joint);

    // 5) vocab projection: [65536, 640] x [640, 4096]^T + b_out -> d_out
    gemm_big<<<(B_ * T_ * U_ / 128) * (V_ / 256), 512, 0, stream>>>(joint, wout_b, out, bout);
}